// Round 2
// baseline (134.925 us; speedup 1.0000x reference)
//
#include <hip/hip_runtime.h>
#include <hip/hip_cooperative_groups.h>
#include <math.h>

namespace cg = cooperative_groups;

constexpr int Lc = 8192;   // sequence length
constexpr int Hc = 4096;   // number of odd taps = L/2
constexpr int Kc = 32;     // eigenvectors
constexpr int Bc = 64;     // batch

// cot(pi*d/L), 1 <= d <= L-1, reflected to avoid cancellation near pi.
__device__ inline float cot_pi_frac(int d) {
    int dd = d; float s = 1.0f;
    if (dd > Lc / 2) { dd = Lc - dd; s = -1.0f; }
    float ang = (float)((double)M_PI * (double)dd * (1.0 / (double)Lc));
    return s * (cosf(ang) / sinf(ang));
}

// Math (validated by R1 pass):
//   result[b] = sr[b]*w[n] + si2[b]*Bp[n]
//   w[n]  = sum_k lam[k] ev[k][n]
//   sr[b] = sum_{even n} u[b][n] + 4096*u[b][0]
//   si2[b]= (2/L) * sum_m u[b][2m+1] * c[m],   c[m] = cot(pi(2m+1)/L)
//   Bp[n] = sum_m c[m] * w[(n-2m-1) mod L]
__global__ __launch_bounds__(256) void fused(
    const float* __restrict__ u, const float* __restrict__ ev,
    const float* __restrict__ lam, float* __restrict__ out,
    float* __restrict__ ws)
{
    float* w   = ws;             // [0, 8192)
    float* c   = ws + 8192;      // [8192, 12288)
    float* sr  = ws + 12288;     // 64
    float* si2 = ws + 12352;     // 64
    float* Bp  = ws + 12416;     // 8 * 8192 partials

    __shared__ float  s_w[1280];
    __shared__ float  s_c[512];
    __shared__ double s_red[8];
    __shared__ float  s_sv[128];

    const int blk = blockIdx.x;
    const int t   = threadIdx.x;
    cg::grid_group grid = cg::this_grid();

    // ---------------- Phase 1: w, sigma, cot table (disjoint blocks) --------
    if (blk < 32) {
        int n = blk * 256 + t;
        float acc = 0.f;
#pragma unroll
        for (int k = 0; k < Kc; ++k)
            acc = fmaf(lam[k], ev[k * Lc + n], acc);
        w[n] = acc;
    } else if (blk < 96) {
        int b = blk - 32;
        const float2* u2 = (const float2*)(u + b * Lc);
        double dar = 0.0, dai = 0.0;
#pragma unroll
        for (int m = t; m < Hc; m += 256) {
            float2 v = u2[m];                   // (u[2m], u[2m+1]) - no divergence
            dar += (double)v.x;
            if (m == 0) dar += 4096.0 * (double)v.x;   // DC bin weight 4097
            dai += (double)v.y * (double)cot_pi_frac(2 * m + 1);
        }
        for (int off = 32; off > 0; off >>= 1) {
            dar += __shfl_down(dar, off);
            dai += __shfl_down(dai, off);
        }
        int wave = t >> 6, lane = t & 63;
        if (lane == 0) { s_red[wave] = dar; s_red[4 + wave] = dai; }
        __syncthreads();
        if (t == 0) {
            sr[b]  = (float)(s_red[0] + s_red[1] + s_red[2] + s_red[3]);
            si2[b] = (float)((s_red[4] + s_red[5] + s_red[6] + s_red[7]) * (2.0 / (double)Lc));
        }
    } else if (blk < 112) {
        int m = (blk - 96) * 256 + t;           // 16 blocks x 256 = 4096
        c[m] = cot_pi_frac(2 * m + 1);
    }
    grid.sync();

    // ---------------- Phase 2: conv partials Bp[cd][n] ----------------------
    {
        int cn = blk & 31, cd = blk >> 5;
        int n0 = cn * 256;          // 256-wide n-chunk
        int m0 = cd * 512;          // 512-tap d-slice
        int base = n0 - 2 * m0 - 1023;
        for (int j = t; j < 1280; j += 256)
            s_w[j] = w[(base + j) & (Lc - 1)];
        for (int j = t; j < 512; j += 256)
            s_c[j] = c[m0 + j];
        __syncthreads();
        float a0 = 0.f, a1 = 0.f, a2 = 0.f, a3 = 0.f;
#pragma unroll 4
        for (int mm = 0; mm < 512; mm += 4) {
            a0 = fmaf(s_c[mm],     s_w[t + 1022 - 2 * mm], a0);
            a1 = fmaf(s_c[mm + 1], s_w[t + 1020 - 2 * mm], a1);
            a2 = fmaf(s_c[mm + 2], s_w[t + 1018 - 2 * mm], a2);
            a3 = fmaf(s_c[mm + 3], s_w[t + 1016 - 2 * mm], a3);
        }
        Bp[cd * Lc + n0 + t] = (a0 + a1) + (a2 + a3);
    }
    grid.sync();

    // ---------------- Phase 3: reduce partials + epilogue -------------------
    {
        if (t < 128) s_sv[t] = (t < 64) ? sr[t] : si2[t - 64];
        __syncthreads();
        int cn = blk & 31, bg = blk >> 5;       // 32 n-chunks x 8 batch-groups
        int n = cn * 256 + t;
        float wv = w[n];
        float bsum = 0.f;
#pragma unroll
        for (int s = 0; s < 8; ++s) bsum += Bp[s * Lc + n];
#pragma unroll
        for (int j = 0; j < 8; ++j) {
            int b = bg * 8 + j;
            out[b * Lc + n] = fmaf(s_sv[b], wv, s_sv[64 + b] * bsum);
        }
    }
}

extern "C" void kernel_launch(void* const* d_in, const int* in_sizes, int n_in,
                              void* d_out, int out_size, void* d_ws, size_t ws_size,
                              hipStream_t stream) {
    const float* u   = (const float*)d_in[0];  // (64, 8192)
    const float* ev  = (const float*)d_in[1];  // (32, 8192)
    const float* lam = (const float*)d_in[2];  // (32,)
    float* out = (float*)d_out;                // (64, 8192)
    float* ws  = (float*)d_ws;

    void* args[] = {(void*)&u, (void*)&ev, (void*)&lam, (void*)&out, (void*)&ws};
    hipLaunchCooperativeKernel(reinterpret_cast<void*>(fused),
                               dim3(256), dim3(256), args, 0, stream);
}

// Round 3
// 65.946 us; speedup vs baseline: 2.0460x; 2.0460x over previous
//
#include <hip/hip_runtime.h>
#include <math.h>

constexpr int Lc = 8192;   // sequence length
constexpr int Kc = 32;     // eigenvectors
constexpr int Bc = 64;     // batch
constexpr int NSLICE = 32; // conv tap-slices (128 odd taps each)
constexpr int NCHUNK = 8;  // conv n-chunks (1024 outputs each)

// cot(pi*d/L) in fp32, reflected for d > L/2 to avoid cancellation near pi.
__device__ inline float cot_pi_frac_f(int d) {
    int dd = d; float s = 1.0f;
    if (dd > Lc / 2) { dd = Lc - dd; s = -1.0f; }
    float ang = (float)(M_PI * (double)dd / (double)Lc);
    return s * __fdividef(__cosf(ang), __sinf(ang));
}

// Math (validated by R1/R2 passes):
//   out[b][n] = sr[b]*w[n] + si2[b]*Bsum[n]
//   w[n]   = sum_k lam[k] ev[k][n]
//   sr[b]  = sum_{even n} u[b][n] + 4096*u[b][0]
//   si2[b] = (2/L) * sum_m u[b][2m+1] * c[m],  c[m] = cot(pi(2m+1)/L)
//   Bsum[n]= sum_m c[m] * w[(n-2m-1) mod L]

// K1: 32 blocks -> w, 16 blocks -> c table, 64 blocks -> sigma. Grid 112.
__global__ __launch_bounds__(256) void k_prep(
    const float* __restrict__ u, const float* __restrict__ ev,
    const float* __restrict__ lam, float* __restrict__ w,
    float* __restrict__ c, float* __restrict__ sr, float* __restrict__ si2)
{
    const int blk = blockIdx.x, t = threadIdx.x;
    if (blk < 32) {
        int n = blk * 256 + t;
        float acc = 0.f;
#pragma unroll
        for (int k = 0; k < Kc; ++k)
            acc = fmaf(lam[k], ev[k * Lc + n], acc);
        w[n] = acc;
    } else if (blk < 48) {
        int m = (blk - 32) * 256 + t;
        c[m] = cot_pi_frac_f(2 * m + 1);
    } else {
        int b = blk - 48;
        const float4* u4 = (const float4*)(u + (size_t)b * Lc);
        float ar0 = 0.f, ar1 = 0.f, ai0 = 0.f, ai1 = 0.f;
#pragma unroll
        for (int i = 0; i < 8; ++i) {
            int j = t + 256 * i;
            float4 v = u4[j];
            ar0 += v.x; ar1 += v.z;
            ai0 = fmaf(v.y, cot_pi_frac_f(4 * j + 1), ai0);
            ai1 = fmaf(v.w, cot_pi_frac_f(4 * j + 3), ai1);
        }
        if (t == 0) ar0 += 4096.0f * u[(size_t)b * Lc];  // DC bin extra weight
        float ar = ar0 + ar1, ai = ai0 + ai1;
        for (int off = 32; off > 0; off >>= 1) {
            ar += __shfl_down(ar, off);
            ai += __shfl_down(ai, off);
        }
        __shared__ float red[8];
        int wave = t >> 6, lane = t & 63;
        if (lane == 0) { red[wave] = ar; red[4 + wave] = ai; }
        __syncthreads();
        if (t == 0) {
            sr[b]  = red[0] + red[1] + red[2] + red[3];
            si2[b] = (2.0f / (float)Lc) * (red[4] + red[5] + red[6] + red[7]);
        }
    }
}

// K2: register-tiled circular FIR over odd taps.
// Grid 256 = 8 n-chunks (1024 wide) x 32 tap-slices (128 taps: d = sl*256+2*mloc+1).
// Thread t: g=t>>1, p=t&1; outputs v(r) = 8g+p+2r, r=0..3 share a 7-reg window.
__global__ __launch_bounds__(256) void k_conv(
    const float* __restrict__ w, const float* __restrict__ c,
    float* __restrict__ Bp)
{
    __shared__ float s_we[641];   // parity-split window; 641 skews s_wo's banks by 1
    __shared__ float s_wo[640];
    __shared__ float s_c[128];

    const int t  = threadIdx.x;
    const int cn = blockIdx.x & (NCHUNK - 1);
    const int sl = blockIdx.x >> 3;
    const int n0 = cn * 1024;
    const int dbase = sl * 256;
    const int wbase = n0 - dbase - 255;   // window covers w[wbase .. wbase+1276]

    for (int j = t; j < 640; j += 256) {
        s_we[j] = w[(wbase + 2 * j + 2 * Lc) & (Lc - 1)];
        s_wo[j] = w[(wbase + 2 * j + 1 + 2 * Lc) & (Lc - 1)];
    }
    if (t < 128) s_c[t] = c[sl * 128 + 127 - t];   // reversed: s_c[mm] = c-tap mloc=127-mm
    __syncthreads();

    const int g = t >> 1, p = t & 1;
    const float* s_wp = p ? s_wo : s_we;
    const int jb = 4 * g;

    float W0 = s_wp[jb],     W1 = s_wp[jb + 1], W2 = s_wp[jb + 2], W3 = s_wp[jb + 3];
    float W4 = s_wp[jb + 4], W5 = s_wp[jb + 5], W6 = s_wp[jb + 6];
    float a0 = 0.f, a1 = 0.f, a2 = 0.f, a3 = 0.f;

#pragma unroll
    for (int G = 0; G < 32; ++G) {
        const int mm0 = 4 * G;
        float c0 = s_c[mm0], c1 = s_c[mm0 + 1], c2 = s_c[mm0 + 2], c3 = s_c[mm0 + 3];
        a0 = fmaf(c0, W0, a0); a1 = fmaf(c0, W1, a1); a2 = fmaf(c0, W2, a2); a3 = fmaf(c0, W3, a3);
        a0 = fmaf(c1, W1, a0); a1 = fmaf(c1, W2, a1); a2 = fmaf(c1, W3, a2); a3 = fmaf(c1, W4, a3);
        a0 = fmaf(c2, W2, a0); a1 = fmaf(c2, W3, a1); a2 = fmaf(c2, W4, a2); a3 = fmaf(c2, W5, a3);
        a0 = fmaf(c3, W3, a0); a1 = fmaf(c3, W4, a1); a2 = fmaf(c3, W5, a2); a3 = fmaf(c3, W6, a3);
        if (G < 31) {
            W0 = W4; W1 = W5; W2 = W6;
            W3 = s_wp[jb + mm0 + 7];  W4 = s_wp[jb + mm0 + 8];
            W5 = s_wp[jb + mm0 + 9];  W6 = s_wp[jb + mm0 + 10];
        }
    }
    float* dst = Bp + (size_t)sl * Lc + n0 + 8 * g + p;
    dst[0] = a0; dst[2] = a1; dst[4] = a2; dst[6] = a3;
}

// K3: reduce 32 partials + rank-2 epilogue. Grid 256 = 32 n-chunks x 8 batch-groups.
__global__ __launch_bounds__(256) void k_out(
    const float* __restrict__ w, const float* __restrict__ sr,
    const float* __restrict__ si2, const float* __restrict__ Bp,
    float* __restrict__ out)
{
    __shared__ float s_sv[128];
    const int t = threadIdx.x;
    if (t < 128) s_sv[t] = (t < 64) ? sr[t] : si2[t - 64];
    const int cn = blockIdx.x & 31, bg = blockIdx.x >> 5;
    const int n = cn * 256 + t;
    float bsum = 0.f;
#pragma unroll
    for (int s = 0; s < NSLICE; ++s) bsum += Bp[(size_t)s * Lc + n];
    float wv = w[n];
    __syncthreads();
#pragma unroll
    for (int j = 0; j < 8; ++j) {
        int b = bg * 8 + j;
        out[(size_t)b * Lc + n] = fmaf(s_sv[b], wv, s_sv[64 + b] * bsum);
    }
}

extern "C" void kernel_launch(void* const* d_in, const int* in_sizes, int n_in,
                              void* d_out, int out_size, void* d_ws, size_t ws_size,
                              hipStream_t stream) {
    const float* u   = (const float*)d_in[0];  // (64, 8192)
    const float* ev  = (const float*)d_in[1];  // (32, 8192)
    const float* lam = (const float*)d_in[2];  // (32,)
    float* out = (float*)d_out;                // (64, 8192)

    float* ws  = (float*)d_ws;
    float* w   = ws;                    // 8192
    float* c   = ws + 8192;             // 4096
    float* sr  = ws + 12288;            // 64
    float* si2 = ws + 12352;            // 64
    float* Bp  = ws + 12416;            // 32 * 8192

    hipLaunchKernelGGL(k_prep, dim3(112), dim3(256), 0, stream, u, ev, lam, w, c, sr, si2);
    hipLaunchKernelGGL(k_conv, dim3(NCHUNK * NSLICE), dim3(256), 0, stream, w, c, Bp);
    hipLaunchKernelGGL(k_out,  dim3(256), dim3(256), 0, stream, w, sr, si2, Bp, out);
}

// Round 4
// 65.655 us; speedup vs baseline: 2.0551x; 1.0044x over previous
//
#include <hip/hip_runtime.h>
#include <math.h>

constexpr int Lc = 8192;   // sequence length
constexpr int Kc = 32;     // eigenvectors
constexpr int Bc = 64;     // batch
constexpr int NSLICE = 32; // conv tap-slices (128 odd taps each)
constexpr int NCHUNK = 8;  // conv n-chunks (1024 outputs each)

// cot(pi*d/L) in fp32, reflected for d > L/2 to avoid cancellation near pi.
__device__ inline float cot_pi_frac_f(int d) {
    int dd = d; float s = 1.0f;
    if (dd > Lc / 2) { dd = Lc - dd; s = -1.0f; }
    float ang = (float)(M_PI * (double)dd / (double)Lc);
    return s * __fdividef(__cosf(ang), __sinf(ang));
}

// Math (validated R1-R3):
//   out[b][n] = sr[b]*w[n] + si2[b]*Bsum[n]
//   w[n]   = sum_k lam[k] ev[k][n]
//   sr[b]  = sum_{even n} u[b][n] + 4096*u[b][0]      (DC weight 4097)
//   si2[b] = (2/L) * sum_m u[b][2m+1] * c[m],  c[m] = cot(pi(2m+1)/L)
//   Bsum[n]= sum_m c[m] * w[(n-2m-1) mod L]           (signs absorbed, see R3)

// K1: blocks 0..63 = sigma (HBM-bound, overlaps), 64..319 = conv slices.
// Conv block: 8 n-chunks (1024 wide) x 32 tap-slices (128 odd taps), w-window
// computed inline from ev (float4 loads), parity-split into LDS.
__global__ __launch_bounds__(256) void k_main(
    const float* __restrict__ u, const float* __restrict__ ev,
    const float* __restrict__ lam, float* __restrict__ sr,
    float* __restrict__ si2, float* __restrict__ Bp)
{
    const int t = threadIdx.x;

    if (blockIdx.x < 64) {
        // ---------------- sigma: per-batch scalar reduction -----------------
        int b = blockIdx.x;
        const float4* u4 = (const float4*)(u + (size_t)b * Lc);
        float ar0 = 0.f, ar1 = 0.f, ai0 = 0.f, ai1 = 0.f;
#pragma unroll
        for (int i = 0; i < 8; ++i) {
            int j = t + 256 * i;
            float4 v = u4[j];
            ar0 += v.x; ar1 += v.z;
            ai0 = fmaf(v.y, cot_pi_frac_f(4 * j + 1), ai0);
            ai1 = fmaf(v.w, cot_pi_frac_f(4 * j + 3), ai1);
        }
        if (t == 0) ar0 += 4096.0f * u[(size_t)b * Lc];
        float ar = ar0 + ar1, ai = ai0 + ai1;
        for (int off = 32; off > 0; off >>= 1) {
            ar += __shfl_down(ar, off);
            ai += __shfl_down(ai, off);
        }
        __shared__ float red[8];
        int wave = t >> 6, lane = t & 63;
        if (lane == 0) { red[wave] = ar; red[4 + wave] = ai; }
        __syncthreads();
        if (t == 0) {
            sr[b]  = red[0] + red[1] + red[2] + red[3];
            si2[b] = (2.0f / (float)Lc) * (red[4] + red[5] + red[6] + red[7]);
        }
        return;
    }

    // ---------------- conv: register-tiled circular FIR ---------------------
    __shared__ float s_we[643];               // s_we[j] = w[A + 2j]
    __shared__ float s_wo[643];               // s_wo[j] = w[A + 2j + 1]
    __shared__ __align__(16) float s_c[128];  // reversed tap slice

    const int blk = blockIdx.x - 64;
    const int cn = blk & (NCHUNK - 1);
    const int sl = blk >> 3;
    const int n0 = cn * 1024;
    const int dbase = sl * 256;
    const int A = n0 - dbase - 256;           // 4-aligned window base

    // Build w-window inline: w[A .. A+1279] via float4 ev loads (320 groups).
#pragma unroll
    for (int it = 0; it < 2; ++it) {
        int gq = t + 256 * it;
        if (gq < 320) {
            int pos = (A + 4 * gq + 2 * Lc) & (Lc - 1);   // 4-aligned, no row cross
            float4 acc = make_float4(0.f, 0.f, 0.f, 0.f);
#pragma unroll
            for (int k = 0; k < Kc; ++k) {
                float4 v = *(const float4*)(ev + (size_t)k * Lc + pos);
                float lk = lam[k];
                acc.x = fmaf(lk, v.x, acc.x); acc.y = fmaf(lk, v.y, acc.y);
                acc.z = fmaf(lk, v.z, acc.z); acc.w = fmaf(lk, v.w, acc.w);
            }
            s_we[2 * gq]     = acc.x; s_wo[2 * gq]     = acc.y;
            s_we[2 * gq + 1] = acc.z; s_wo[2 * gq + 1] = acc.w;
        }
    }
    // Reversed tap slice: s_c[mm] = cot(pi*(dbase + 255 - 2mm)/L)
    if (t < 128) s_c[t] = cot_pi_frac_f(dbase + 255 - 2 * t);
    __syncthreads();

    // Thread t: g=t>>1, p=t&1; outputs n0+8g+p+2r, r=0..3, shared 7-reg window.
    const int g = t >> 1, p = t & 1;
    const float* s_wp = p ? (s_we + 1) : s_wo;   // parity remap vs R3 (A=wbase-1)
    const int jb = 4 * g;

    float W0 = s_wp[jb],     W1 = s_wp[jb + 1], W2 = s_wp[jb + 2], W3 = s_wp[jb + 3];
    float W4 = s_wp[jb + 4], W5 = s_wp[jb + 5], W6 = s_wp[jb + 6];
    float a0 = 0.f, a1 = 0.f, a2 = 0.f, a3 = 0.f;

    const float4* s_c4 = (const float4*)s_c;
#pragma unroll
    for (int G = 0; G < 32; ++G) {
        const int mm0 = 4 * G;
        float4 cv = s_c4[G];                     // one ds_read_b128
        a0 = fmaf(cv.x, W0, a0); a1 = fmaf(cv.x, W1, a1); a2 = fmaf(cv.x, W2, a2); a3 = fmaf(cv.x, W3, a3);
        a0 = fmaf(cv.y, W1, a0); a1 = fmaf(cv.y, W2, a1); a2 = fmaf(cv.y, W3, a2); a3 = fmaf(cv.y, W4, a3);
        a0 = fmaf(cv.z, W2, a0); a1 = fmaf(cv.z, W3, a1); a2 = fmaf(cv.z, W4, a2); a3 = fmaf(cv.z, W5, a3);
        a0 = fmaf(cv.w, W3, a0); a1 = fmaf(cv.w, W4, a1); a2 = fmaf(cv.w, W5, a2); a3 = fmaf(cv.w, W6, a3);
        if (G < 31) {
            W0 = W4; W1 = W5; W2 = W6;
            W3 = s_wp[jb + mm0 + 7];  W4 = s_wp[jb + mm0 + 8];
            W5 = s_wp[jb + mm0 + 9];  W6 = s_wp[jb + mm0 + 10];
        }
    }
    float* dst = Bp + (size_t)sl * Lc + n0 + 8 * g + p;
    dst[0] = a0; dst[2] = a1; dst[4] = a2; dst[6] = a3;
}

// K2: reduce 32 partials + rank-2 epilogue; w recomputed inline (L2/L3-hot ev).
__global__ __launch_bounds__(256) void k_out(
    const float* __restrict__ ev, const float* __restrict__ lam,
    const float* __restrict__ sr, const float* __restrict__ si2,
    const float* __restrict__ Bp, float* __restrict__ out)
{
    __shared__ float s_sv[128];
    const int t = threadIdx.x;
    if (t < 128) s_sv[t] = (t < 64) ? sr[t] : si2[t - 64];
    const int cn = blockIdx.x & 31, bg = blockIdx.x >> 5;
    const int n = cn * 256 + t;
    float wv = 0.f;
#pragma unroll
    for (int k = 0; k < Kc; ++k)
        wv = fmaf(lam[k], ev[(size_t)k * Lc + n], wv);
    float bsum = 0.f;
#pragma unroll
    for (int s = 0; s < NSLICE; ++s) bsum += Bp[(size_t)s * Lc + n];
    __syncthreads();
#pragma unroll
    for (int j = 0; j < 8; ++j) {
        int b = bg * 8 + j;
        out[(size_t)b * Lc + n] = fmaf(s_sv[b], wv, s_sv[64 + b] * bsum);
    }
}

extern "C" void kernel_launch(void* const* d_in, const int* in_sizes, int n_in,
                              void* d_out, int out_size, void* d_ws, size_t ws_size,
                              hipStream_t stream) {
    const float* u   = (const float*)d_in[0];  // (64, 8192)
    const float* ev  = (const float*)d_in[1];  // (32, 8192)
    const float* lam = (const float*)d_in[2];  // (32,)
    float* out = (float*)d_out;                // (64, 8192)

    float* ws  = (float*)d_ws;
    float* sr  = ws;                    // 64
    float* si2 = ws + 64;               // 64
    float* Bp  = ws + 128;              // 32 * 8192

    hipLaunchKernelGGL(k_main, dim3(64 + NCHUNK * NSLICE), dim3(256), 0, stream,
                       u, ev, lam, sr, si2, Bp);
    hipLaunchKernelGGL(k_out, dim3(256), dim3(256), 0, stream,
                       ev, lam, sr, si2, Bp, out);
}